// Round 6
// baseline (67.901 us; speedup 1.0000x reference)
//
#include <hip/hip_runtime.h>
#include <stdint.h>

typedef _Float16 half4_t __attribute__((ext_vector_type(4)));
typedef float floatx4 __attribute__((ext_vector_type(4)));

static constexpr int HW  = 128;
static constexpr int DD  = 64;
static constexpr int RPB = 64;   // rows per block (half of 128)
static constexpr int SV  = 68;   // padded VL row stride in f32 (272 B, 16B-aligned)

typedef const __attribute__((address_space(1))) uint32_t GU;
typedef __attribute__((address_space(3))) uint32_t LU;

// Block = (b, rc, half h): 64 rows x 64 cols of OUT = softmax(logits) @ V.
// 8 waves (512 thr): wave = (row-group gr = w>>1 -> 16 rows, col-group gc = w&1 -> 32 cols).
// P never exists in memory: softmax is computed fully in registers in MFMA
// A-fragment layout (lane owns row lane&15, j = 16t+4(lane>>4)+i).
// Atten: 8 inline-asm global_load_dwordx4 per lane (issue pinned at top),
//        counted s_waitcnt vmcnt(16) -> softmax starts while V streams in.
// V: LDS rows padded to 68 f32 via 16-lane global_load_lds (per-row dest) ->
//    B-fragment b32 reads are exactly 2-way bank aliased = free.
// X: brc=(b,r), V=v[b,r,:,:] (row 256B, contiguous).  out = P@V
// Y: brc=(b,c), V=v[b,:,c,:] (row stride 32KB); out += (preload into acc).
template<bool IS_Y>
__global__ __launch_bounds__(512, 4)
void axial_attn(const float* __restrict__ atten,
                const float* __restrict__ vsrc,
                const float* __restrict__ shift_p,
                float* __restrict__ out)
{
    __shared__ float VL[HW * SV];   // 34.8 KB

    const int blk   = blockIdx.x;
    const int h     = blk & 1;      // halves adjacent -> V L2/L3 reuse
    const int brc   = blk >> 1;
    const int b     = brc >> 7;
    const int rc    = brc & 127;
    const int rbase = h * RPB;
    const int tid   = threadIdx.x;
    const int w     = tid >> 6;
    const int lane  = tid & 63;
    const int lr    = lane & 15;
    const int g     = lane >> 4;    // 0..3
    const int gr    = w >> 1;       // row-group 0..3
    const int gc    = w & 1;        // col-group 0..1
    const int grow  = rbase + 16 * gr + lr;   // this lane's softmax row

    // ---- 1) issue atten loads (pinned, in order) ----
    const float* arow = atten + (size_t)brc * (HW * HW) + (size_t)grow * HW + g * 4;
    floatx4 a0, a1, a2, a3, a4, a5, a6, a7;
    asm volatile("global_load_dwordx4 %0, %1, off"             : "=v"(a0) : "v"(arow) : "memory");
    asm volatile("global_load_dwordx4 %0, %1, off offset:64"   : "=v"(a1) : "v"(arow) : "memory");
    asm volatile("global_load_dwordx4 %0, %1, off offset:128"  : "=v"(a2) : "v"(arow) : "memory");
    asm volatile("global_load_dwordx4 %0, %1, off offset:192"  : "=v"(a3) : "v"(arow) : "memory");
    asm volatile("global_load_dwordx4 %0, %1, off offset:256"  : "=v"(a4) : "v"(arow) : "memory");
    asm volatile("global_load_dwordx4 %0, %1, off offset:320"  : "=v"(a5) : "v"(arow) : "memory");
    asm volatile("global_load_dwordx4 %0, %1, off offset:384"  : "=v"(a6) : "v"(arow) : "memory");
    asm volatile("global_load_dwordx4 %0, %1, off offset:448"  : "=v"(a7) : "v"(arow) : "memory");

    // ---- 2) stage V rows into padded LDS (16 lanes x 16B = one 256B row) ----
    {
        const char* vg = IS_Y ? (const char*)(vsrc + ((size_t)b * HW * HW + rc) * DD)
                              : (const char*)(vsrc + (size_t)brc * (HW * DD));
        char* vl = (char*)VL;
        if (lane < 16) {
            #pragma unroll
            for (int i = 0; i < 16; ++i) {
                const int k = w * 16 + i;              // wave w stages rows [16w..16w+16)
                const size_t gs = IS_Y ? (size_t)k * (HW * DD * 4) : (size_t)k * (DD * 4);
                __builtin_amdgcn_global_load_lds((GU*)(vg + gs + lane * 16),
                                                 (LU*)(vl + k * (SV * 4)), 16, 0, 0);
            }
        }
    }

    // ---- 3) wait for this wave's 8 atten loads only (16 V loads in flight) ----
    asm volatile("s_waitcnt vmcnt(16)" ::: "memory");
    __builtin_amdgcn_sched_barrier(0);

    // ---- 4) Y: out-preload into acc (issued now, consumed after barrier) ----
    float* obase;
    size_t ostr;
    if (IS_Y) { obase = out + (size_t)b * (HW * HW * DD) + (size_t)rc * DD; ostr = HW * DD; }
    else      { obase = out + (size_t)brc * (HW * DD);                      ostr = DD;      }
    const int dcol = 32 * gc + lr;
    floatx4 acc[2];
    if (IS_Y) {
        #pragma unroll
        for (int s = 0; s < 2; ++s)
            #pragma unroll
            for (int i = 0; i < 4; ++i)
                acc[s][i] = obase[(size_t)(rbase + 16 * gr + 4 * g + i) * ostr + dcol + 16 * s];
    } else {
        acc[0] = (floatx4)(0.f);
        acc[1] = (floatx4)(0.f);
    }

    const float shift = shift_p[0];   // bias cancels in softmax

    // ---- 5) in-register softmax of row `grow` (4 lanes per row) ----
    const floatx4 av[8] = {a0, a1, a2, a3, a4, a5, a6, a7};
    float l[32];
    #pragma unroll
    for (int t = 0; t < 8; ++t)
        #pragma unroll
        for (int i = 0; i < 4; ++i) {
            const float d = (float)(16 * t + 4 * g + i - grow);
            l[t * 4 + i] = fmaf(-shift * d, d, av[t][i]);
        }
    float m16[16];
    #pragma unroll
    for (int i = 0; i < 16; ++i) m16[i] = fmaxf(l[i], l[i + 16]);
    #pragma unroll
    for (int s = 8; s >= 1; s >>= 1)
        #pragma unroll
        for (int i = 0; i < s; ++i) m16[i] = fmaxf(m16[i], m16[i + s]);
    float mx = m16[0];
    mx = fmaxf(mx, __shfl_xor(mx, 16));
    mx = fmaxf(mx, __shfl_xor(mx, 32));

    float e[32];
    #pragma unroll
    for (int t = 0; t < 32; ++t) e[t] = __expf(l[t] - mx);
    float s16[16];
    #pragma unroll
    for (int i = 0; i < 16; ++i) s16[i] = e[i] + e[i + 16];
    #pragma unroll
    for (int s = 8; s >= 1; s >>= 1)
        #pragma unroll
        for (int i = 0; i < s; ++i) s16[i] += s16[i + s];
    float sum = s16[0];
    sum += __shfl_xor(sum, 16);
    sum += __shfl_xor(sum, 32);
    const float inv = 1.0f / sum;

    half4_t af[8];
    #pragma unroll
    for (int t = 0; t < 8; ++t)
        #pragma unroll
        for (int i = 0; i < 4; ++i)
            af[t][i] = (_Float16)(e[t * 4 + i] * inv);

    __syncthreads();   // drains vmcnt(0): VL ready for all waves

    // ---- 6) MFMA: A from regs, B from padded VL (2-way = conflict-free) ----
    // A[row=lane&15][k=4g+i], B[k][col=lane&15], D[col][row=4g+i]
    #pragma unroll
    for (int t = 0; t < 8; ++t) {
        #pragma unroll
        for (int s = 0; s < 2; ++s) {
            half4_t bf;
            #pragma unroll
            for (int i = 0; i < 4; ++i)
                bf[i] = (_Float16)VL[(16 * t + 4 * g + i) * SV + dcol + 16 * s];
            acc[s] = __builtin_amdgcn_mfma_f32_16x16x16f16(af[t], bf, acc[s], 0, 0, 0);
        }
    }

    // ---- 7) store: row = rbase+16gr+4g+i, col = dcol+16s ----
    #pragma unroll
    for (int s = 0; s < 2; ++s)
        #pragma unroll
        for (int i = 0; i < 4; ++i)
            obase[(size_t)(rbase + 16 * gr + 4 * g + i) * ostr + dcol + 16 * s] = acc[s][i];
}

extern "C" void kernel_launch(void* const* d_in, const int* in_sizes, int n_in,
                              void* d_out, int out_size, void* d_ws, size_t ws_size,
                              hipStream_t stream)
{
    // inputs: 0=x (unused), 1=atten_x_full, 2=atten_y_full, 3=value_full, 4=shift, 5=bias (cancels)
    const float* atx   = (const float*)d_in[1];
    const float* aty   = (const float*)d_in[2];
    const float* val   = (const float*)d_in[3];
    const float* shift = (const float*)d_in[4];
    float* out = (float*)d_out;

    axial_attn<false><<<dim3(8 * 128 * 2), dim3(512), 0, stream>>>(atx, val, shift, out);
    axial_attn<true ><<<dim3(8 * 128 * 2), dim3(512), 0, stream>>>(aty, val, shift, out);
}

// Round 8
// 59.776 us; speedup vs baseline: 1.1359x; 1.1359x over previous
//
#include <hip/hip_runtime.h>
#include <stdint.h>

typedef _Float16 half4_t __attribute__((ext_vector_type(4)));
typedef float    floatx4 __attribute__((ext_vector_type(4)));

static constexpr int HW = 128;
static constexpr int DD = 64;

#define GLOAD4O(dst, ptr, o) asm volatile("global_load_dwordx4 %0, %1, off offset:" #o : "=v"(dst) : "v"(ptr) : "memory")
#define GLOAD1O(dst, ptr, o) asm volatile("global_load_dword %0, %1, off offset:" #o   : "=v"(dst) : "v"(ptr) : "memory")
#define WAITV(n) do { asm volatile("s_waitcnt vmcnt(" #n ")" ::: "memory"); \
                      __builtin_amdgcn_sched_barrier(0); } while (0)

// Load one k-tile t of V^T A-fragments: dst[i][dt] = v[16t+4g+i][16dt+lr]
// (4 base ptrs, dt via 64B imm offsets; 16 scalar dwords, 64B-coalesced per 16-lane group)
#define LOADT(t_, dst) do { \
    const float* p0_ = vX + (size_t)(16*(t_) + 4*g + 0) * vstr; \
    const float* p1_ = vX + (size_t)(16*(t_) + 4*g + 1) * vstr; \
    const float* p2_ = vX + (size_t)(16*(t_) + 4*g + 2) * vstr; \
    const float* p3_ = vX + (size_t)(16*(t_) + 4*g + 3) * vstr; \
    GLOAD1O(dst[0][0], p0_, 0); GLOAD1O(dst[0][1], p0_, 64); GLOAD1O(dst[0][2], p0_, 128); GLOAD1O(dst[0][3], p0_, 192); \
    GLOAD1O(dst[1][0], p1_, 0); GLOAD1O(dst[1][1], p1_, 64); GLOAD1O(dst[1][2], p1_, 128); GLOAD1O(dst[1][3], p1_, 192); \
    GLOAD1O(dst[2][0], p2_, 0); GLOAD1O(dst[2][1], p2_, 64); GLOAD1O(dst[2][2], p2_, 128); GLOAD1O(dst[2][3], p2_, 192); \
    GLOAD1O(dst[3][0], p3_, 0); GLOAD1O(dst[3][1], p3_, 64); GLOAD1O(dst[3][2], p3_, 128); GLOAD1O(dst[3][3], p3_, 192); \
} while (0)

// Convert a 2-t-tile chunk of raw f32 to half4 A-fragments (compiler packs cvt).
#define CVTC(vf_, c_) do { _Pragma("unroll") for (int tt = 0; tt < 2; ++tt) \
    { _Pragma("unroll") for (int dt = 0; dt < 4; ++dt) { \
        vf_[tt][dt][0] = (_Float16)c_[tt][0][dt]; \
        vf_[tt][dt][1] = (_Float16)c_[tt][1][dt]; \
        vf_[tt][dt][2] = (_Float16)c_[tt][2][dt]; \
        vf_[tt][dt][3] = (_Float16)c_[tt][3][dt]; } } } while (0)

// D^T = V^T (A) x P^T (B): acc[dt] covers d=16dt+4g+i, c(row)=grow.
#define MFMAC(vf_, t0_) do { _Pragma("unroll") for (int tt = 0; tt < 2; ++tt) \
    { _Pragma("unroll") for (int dt = 0; dt < 4; ++dt) \
        acc[dt] = __builtin_amdgcn_mfma_f32_16x16x16f16(vf_[tt][dt], af[(t0_) + tt], acc[dt], 0, 0, 0); } } while (0)

// Block = (b, rc, half h): 64 output rows; 4 independent waves, 16 rows each.
// NO LDS, NO barrier. Per wave: pinned asm loads (atten 8x dwordx4; V^T 128
// scalar dwords in 4 chunks), counted vmcnt pipeline, in-register softmax whose
// A-fragments serve as the MFMA *B* operand (P^T), V^T fragments as A.
// X: brc=(b,r), rows are c, V=v[b,r,:,:] (k-stride 64).   out = P@V
// Y: brc=(b,c), rows are r, V=v[b,:,c,:] (k-stride 8192); out += (dwordx4 preload).
template<bool IS_Y>
__global__ __launch_bounds__(256, 3)
void axial_attn(const float* __restrict__ atten,
                const float* __restrict__ vsrc,
                const float* __restrict__ shift_p,
                float* __restrict__ out)
{
    const int blk  = blockIdx.x;
    const int h    = blk & 1;
    const int brc  = blk >> 1;
    const int b    = brc >> 7;
    const int rc   = brc & 127;
    const int tid  = threadIdx.x;
    const int w    = tid >> 6;
    const int lane = tid & 63;
    const int lr   = lane & 15;
    const int g    = lane >> 4;             // 0..3
    const int grow = h * 64 + w * 16 + lr;  // this lane's softmax/output row

    // ---- issue: atten (8x dwordx4, rows owned exclusively by this wave) ----
    const float* arow = atten + (size_t)brc * (HW * HW) + (size_t)grow * HW + g * 4;
    floatx4 a0, a1, a2, a3, a4, a5, a6, a7;
    GLOAD4O(a0, arow, 0);   GLOAD4O(a1, arow, 64);  GLOAD4O(a2, arow, 128); GLOAD4O(a3, arow, 192);
    GLOAD4O(a4, arow, 256); GLOAD4O(a5, arow, 320); GLOAD4O(a6, arow, 384); GLOAD4O(a7, arow, 448);

    // ---- issue: V^T chunk 0 (t = 0,1) ----
    const float* vX   = IS_Y ? vsrc + ((size_t)b * HW * HW + rc) * DD + lr
                             : vsrc + (size_t)brc * (HW * DD) + lr;
    const int    vstr = IS_Y ? HW * DD : DD;
    float cA[2][4][4], cB[2][4][4];         // [tt][i][dt], ping-pong
    LOADT(0, cA[0]); LOADT(1, cA[1]);

    // ---- issue: Y out-preload (4x dwordx4) ----
    float* ob = IS_Y ? out + (size_t)b * (HW * HW * DD) + (size_t)grow * (HW * DD) + rc * DD
                     : out + (size_t)brc * (HW * DD) + (size_t)grow * DD;
    floatx4 acc[4];
    if (IS_Y) {
        const float* pb = ob + 4 * g;
        GLOAD4O(acc[0], pb, 0); GLOAD4O(acc[1], pb, 64);
        GLOAD4O(acc[2], pb, 128); GLOAD4O(acc[3], pb, 192);
    } else {
        #pragma unroll
        for (int dt = 0; dt < 4; ++dt) acc[dt] = (floatx4)(0.f);
    }

    // ---- wait: atten only (chunk0 [+preload] stay in flight) ----
    if constexpr (IS_Y) { WAITV(36); } else { WAITV(32); }

    const float shift = shift_p[0];         // bias cancels in softmax

    // ---- in-register softmax of row `grow` (4 lanes per row, j = 16t+4g+i) ----
    const floatx4 av[8] = {a0, a1, a2, a3, a4, a5, a6, a7};
    float l[32];
    #pragma unroll
    for (int t = 0; t < 8; ++t)
        #pragma unroll
        for (int i = 0; i < 4; ++i) {
            const float d = (float)(16 * t + 4 * g + i - grow);
            l[t * 4 + i] = fmaf(-shift * d, d, av[t][i]);
        }
    float m16[16];
    #pragma unroll
    for (int i = 0; i < 16; ++i) m16[i] = fmaxf(l[i], l[i + 16]);
    #pragma unroll
    for (int s = 8; s >= 1; s >>= 1)
        #pragma unroll
        for (int i = 0; i < s; ++i) m16[i] = fmaxf(m16[i], m16[i + s]);
    float mx = m16[0];
    mx = fmaxf(mx, __shfl_xor(mx, 16));
    mx = fmaxf(mx, __shfl_xor(mx, 32));

    float e[32];
    #pragma unroll
    for (int t = 0; t < 32; ++t) e[t] = __expf(l[t] - mx);
    float s16[16];
    #pragma unroll
    for (int i = 0; i < 16; ++i) s16[i] = e[i] + e[i + 16];
    #pragma unroll
    for (int s = 8; s >= 1; s >>= 1)
        #pragma unroll
        for (int i = 0; i < s; ++i) s16[i] += s16[i + s];
    float sum = s16[0];
    sum += __shfl_xor(sum, 16);
    sum += __shfl_xor(sum, 32);
    const float inv = 1.0f / sum;

    half4_t af[8];                           // P A-frag == P^T B-frag (same lane map)
    #pragma unroll
    for (int t = 0; t < 8; ++t)
        #pragma unroll
        for (int i = 0; i < 4; ++i)
            af[t][i] = (_Float16)(e[4 * t + i] * inv);

    // ---- pipelined V^T chunks: issue next, wait current(32), convert, MFMA ----
    half4_t vf[2][4];
    LOADT(2, cB[0]); LOADT(3, cB[1]);
    WAITV(32);                // chunk0 (+Y preload) done
    CVTC(vf, cA); MFMAC(vf, 0);

    LOADT(4, cA[0]); LOADT(5, cA[1]);
    WAITV(32);                // chunk1 done
    CVTC(vf, cB); MFMAC(vf, 2);

    LOADT(6, cB[0]); LOADT(7, cB[1]);
    WAITV(32);                // chunk2 done
    CVTC(vf, cA); MFMAC(vf, 4);

    WAITV(0);                 // chunk3 done
    CVTC(vf, cB); MFMAC(vf, 6);

    // ---- store: lane holds out[row=grow][d=16dt+4g+i] -> 4x dwordx4 ----
    #pragma unroll
    for (int dt = 0; dt < 4; ++dt)
        *(floatx4*)&ob[16 * dt + 4 * g] = acc[dt];
}

extern "C" void kernel_launch(void* const* d_in, const int* in_sizes, int n_in,
                              void* d_out, int out_size, void* d_ws, size_t ws_size,
                              hipStream_t stream)
{
    // inputs: 0=x (unused), 1=atten_x_full, 2=atten_y_full, 3=value_full, 4=shift, 5=bias (cancels)
    const float* atx   = (const float*)d_in[1];
    const float* aty   = (const float*)d_in[2];
    const float* val   = (const float*)d_in[3];
    const float* shift = (const float*)d_in[4];
    float* out = (float*)d_out;

    axial_attn<false><<<dim3(8 * 128 * 2), dim3(256), 0, stream>>>(atx, val, shift, out);
    axial_attn<true ><<<dim3(8 * 128 * 2), dim3(256), 0, stream>>>(aty, val, shift, out);
}